// Round 12
// baseline (38.080 us; speedup 1.0000x reference)
//
#include <hip/hip_runtime.h>

// SubtitleColorConsistencyLoss — MI355X (gfx950)
// R11 = R10 with the compile fix: nontemporal loads via clang ext_vector_type
//      (HIP float4 is a class and rejected by the builtin). Otherwise R8.

namespace {
constexpr int NIMG = 8;
constexpr int NCH  = 16;
constexpr int HWPX = 512 * 512;
constexpr int KSEG = 65;                 // labels 0..64; slot 0 = background
constexpr int NF   = 18;                 // [0]=count [1]=sqsum [2..17]=sums
constexpr int SPANS = HWPX / 64;         // 4096 spans per image
constexpr int TABF  = NIMG * KSEG * NF;  // 9360 floats
constexpr int WS_TAB = NIMG * SPANS;     // 32768
constexpr float EPSV   = 1e-6f;
constexpr float MARGIN = 0.5f;
constexpr float LAMBDA = 0.4f;
constexpr float MINPIX = 20.0f;
typedef float fx4 __attribute__((ext_vector_type(4)));
}

// Pass A: span-label compression (uniform 64-px span -> label, else -1)
//         + zero the global table (image-0 blocks, plain stores).
__global__ __launch_bounds__(256) void spanlab_kernel(
    const int* __restrict__ labels, int* __restrict__ spanlab,
    float* __restrict__ tab)
{
    const int n   = blockIdx.y;
    const int tid = threadIdx.x;
    const int grp = tid >> 4, l16 = tid & 15, wgrp = (tid & 63) >> 4;
    const int span = blockIdx.x * 16 + grp;
    const int p    = span * 64 + l16 * 4;

    if (n == 0 && tid < 37) {
        const int idx = blockIdx.x * 37 + tid;
        if (idx < TABF) tab[idx] = 0.0f;
    }

    const int4 lab = *reinterpret_cast<const int4*>(labels + (size_t)n * HWPX + p);
    const int  lab0 = __shfl(lab.x, 0, 16);
    const bool uni  = (lab.x == lab.y) && (lab.x == lab.z) &&
                      (lab.x == lab.w) && (lab.x == lab0);
    const unsigned long long b = __ballot((int)uni);
    const unsigned long long m = 0xFFFFull << (wgrp * 16);
    if (l16 == 0)
        spanlab[n * SPANS + span] = ((b & m) == m) ? lab0 : -1;
}

__global__ __launch_bounds__(256) void accum_kernel(
    const float* __restrict__ color,
    const int*   __restrict__ labels,
    const int*   __restrict__ spanlab,
    float* __restrict__ tab)
{
    __shared__ float ltab[KSEG * NF];
    const int tid = threadIdx.x;
    for (int i = tid; i < KSEG * NF; i += 256) ltab[i] = 0.0f;
    __syncthreads();

    const int n = blockIdx.y;
    const float* colN = color  + (size_t)n * NCH * HWPX;
    const int*   labN = labels + (size_t)n * HWPX;
    const int*   slN  = spanlab + n * SPANS;

    const int grp = tid >> 4;           // 16-lane group -> one 64-px span
    const int l16 = tid & 15;

    const int stride = gridDim.x * 1024;   // 256 threads * 4 px
    for (int base = blockIdx.x * 1024; base < HWPX; base += stride) {
        const int span = (base >> 6) + grp;
        const int p    = base + grp * 64 + l16 * 4;
        const int slab = slN[span];        // one cached dword per group

        if (slab >= 0) {
            // fast path: uniform span, label known. Nontemporal stream loads
            // (data is read exactly once; skip cache allocation).
            float fs[NCH];
            float sq = 0.0f;
            #pragma unroll
            for (int c = 0; c < NCH; ++c) {
                const fx4 v = __builtin_nontemporal_load(
                    reinterpret_cast<const fx4*>(colN + (size_t)c * HWPX + p));
                fs[c] = (v.x + v.y) + (v.z + v.w);
                sq += v.x * v.x + v.y * v.y + v.z * v.z + v.w * v.w;
            }
            // reduce-scatter: lane l ends owning channel l's span total
            #pragma unroll
            for (int c = 0; c < 8; ++c) {
                const float snd = (l16 & 8) ? fs[c] : fs[c + 8];
                const float kp  = (l16 & 8) ? fs[c + 8] : fs[c];
                fs[c] = kp + __shfl_xor(snd, 8, 16);
            }
            #pragma unroll
            for (int c = 0; c < 4; ++c) {
                const float snd = (l16 & 4) ? fs[c] : fs[c + 4];
                const float kp  = (l16 & 4) ? fs[c + 4] : fs[c];
                fs[c] = kp + __shfl_xor(snd, 4, 16);
            }
            #pragma unroll
            for (int c = 0; c < 2; ++c) {
                const float snd = (l16 & 2) ? fs[c] : fs[c + 2];
                const float kp  = (l16 & 2) ? fs[c + 2] : fs[c];
                fs[c] = kp + __shfl_xor(snd, 2, 16);
            }
            {
                const float snd = (l16 & 1) ? fs[0] : fs[1];
                const float kp  = (l16 & 1) ? fs[1] : fs[0];
                fs[0] = kp + __shfl_xor(snd, 1, 16);
            }
            sq += __shfl_xor(sq, 8, 16);
            sq += __shfl_xor(sq, 4, 16);
            sq += __shfl_xor(sq, 2, 16);
            sq += __shfl_xor(sq, 1, 16);

            float* seg = ltab + slab * NF;
            atomicAdd(seg + 2 + l16, fs[0]);   // 16 lanes, consecutive addrs
            if (l16 == 0) {
                atomicAdd(seg + 0, 64.0f);
                atomicAdd(seg + 1, sq);
            }
        } else {
            // correctness fallback: per-pixel LDS atomics (never on this data)
            const int4 lb = *reinterpret_cast<const int4*>(labN + p);
            const int labv[4] = {lb.x, lb.y, lb.z, lb.w};
            for (int i = 0; i < 4; ++i) {
                float sqp = 0.0f;
                float* seg = ltab + labv[i] * NF;
                for (int c = 0; c < NCH; ++c) {
                    const float x = colN[(size_t)c * HWPX + p + i];
                    sqp += x * x;
                    atomicAdd(seg + 2 + c, x);
                }
                atomicAdd(seg + 0, 1.0f);
                atomicAdd(seg + 1, sqp);
            }
        }
    }

    __syncthreads();
    // flush (typically 1-2 nonzero segments per block)
    float* tabN = tab + (size_t)n * KSEG * NF;
    for (int i = tid; i < KSEG * NF; i += 256) {
        const float x = ltab[i];
        if (x != 0.0f) atomicAdd(tabN + i, x);
    }
}

__global__ __launch_bounds__(256) void finalize_kernel(
    const float* __restrict__ tab, float* __restrict__ out)
{
    __shared__ float mbg[NIMG][NCH];
    __shared__ float bgcnt[NIMG];
    __shared__ float r0[256], r1[256], r2[256];
    const int tid = threadIdx.x;
    if (tid < NIMG * NCH) {
        const int n = tid / NCH, c = tid % NCH;
        const float* b = tab + (size_t)n * KSEG * NF;   // slot 0 = background
        const float cnt = b[0];
        mbg[n][c] = b[2 + c] / (cnt + EPSV);
        if (c == 0) bgcnt[n] = cnt;
    }
    __syncthreads();

    float vsum = 0.0f, intraS = 0.0f, interS = 0.0f;
    for (int idx = tid; idx < NIMG * KSEG; idx += 256) {
        const int n = idx / KSEG, k = idx % KSEG;
        if (k == 0) continue;
        const float* s = tab + ((size_t)n * KSEG + k) * NF;
        const float cnt = s[0], sq = s[1];
        const float denom = cnt + EPSV;
        float d2 = 0.0f, msf = 0.0f, msm = 0.0f;
        #pragma unroll
        for (int c = 0; c < NCH; ++c) {
            const float f  = s[2 + c];
            const float mu = f / denom;
            msf += mu * f;
            msm += mu * mu;
            const float dd = mu - mbg[n][c];
            d2 += dd * dd;
        }
        const float intra = (sq - 2.0f * msf + cnt * msm) / denom;
        const float dist  = sqrtf(d2 + 1e-12f);
        const float t     = fmaxf(MARGIN - dist, 0.0f);
        const float inter = t * t;
        if ((cnt >= MINPIX) && (bgcnt[n] >= MINPIX)) {
            vsum += 1.0f; intraS += intra; interS += inter;
        }
    }
    r0[tid] = vsum; r1[tid] = intraS; r2[tid] = interS;
    __syncthreads();
    for (int sft = 128; sft; sft >>= 1) {
        if (tid < sft) {
            r0[tid] += r0[tid + sft];
            r1[tid] += r1[tid + sft];
            r2[tid] += r2[tid + sft];
        }
        __syncthreads();
    }
    if (tid == 0) {
        const float total = r0[0];
        const float safe  = fmaxf(total, 1.0f);
        out[0] = (total > 0.0f) ? (r1[0] + LAMBDA * r2[0]) / safe : 0.0f;
    }
}

extern "C" void kernel_launch(void* const* d_in, const int* in_sizes, int n_in,
                              void* d_out, int out_size, void* d_ws, size_t ws_size,
                              hipStream_t stream) {
    const float* color  = (const float*)d_in[0];
    const int*   labels = (const int*)d_in[2];
    float* ws  = (float*)d_ws;
    float* out = (float*)d_out;

    int*   spanlab = (int*)ws;
    float* tab     = ws + WS_TAB;

    dim3 gridA(SPANS / 16, NIMG);    // 256 x 8 blocks; also zeroes tab
    spanlab_kernel<<<gridA, 256, 0, stream>>>(labels, spanlab, tab);

    dim3 gridB(128, NIMG);           // 1024 blocks, grid-stride x2 (R8 proven)
    accum_kernel<<<gridB, 256, 0, stream>>>(color, labels, spanlab, tab);

    finalize_kernel<<<1, 256, 0, stream>>>(tab, out);
}

// Round 13
// 37.323 us; speedup vs baseline: 1.0203x; 1.0203x over previous
//
#include <hip/hip_runtime.h>

// SubtitleColorConsistencyLoss — MI355X (gfx950)
// R12: occupancy experiment. Group = 16 lanes x 8 CHANNELS (half a span);
//      two groups per span -> per-lane state halves (8 float4 in flight,
//      fs[8]) -> VGPR <= 64 -> 8 waves/SIMD (vs 6). No ballot anywhere.
//      Else identical to R8 (proven best). Tests outstanding-load capacity.

namespace {
constexpr int NIMG = 8;
constexpr int NCH  = 16;
constexpr int HWPX = 512 * 512;
constexpr int KSEG = 65;                 // labels 0..64; slot 0 = background
constexpr int NF   = 18;                 // [0]=count [1]=sqsum [2..17]=sums
constexpr int SPANS = HWPX / 64;         // 4096 spans per image
constexpr int TABF  = NIMG * KSEG * NF;  // 9360 floats
constexpr int WS_TAB = NIMG * SPANS;     // 32768
constexpr float EPSV   = 1e-6f;
constexpr float MARGIN = 0.5f;
constexpr float LAMBDA = 0.4f;
constexpr float MINPIX = 20.0f;
}

// Pass A: span-label compression (uniform 64-px span -> label, else -1)
//         + zero the global table (image-0 blocks, plain stores).
__global__ __launch_bounds__(256) void spanlab_kernel(
    const int* __restrict__ labels, int* __restrict__ spanlab,
    float* __restrict__ tab)
{
    const int n   = blockIdx.y;
    const int tid = threadIdx.x;
    const int grp = tid >> 4, l16 = tid & 15, wgrp = (tid & 63) >> 4;
    const int span = blockIdx.x * 16 + grp;
    const int p    = span * 64 + l16 * 4;

    if (n == 0 && tid < 37) {
        const int idx = blockIdx.x * 37 + tid;
        if (idx < TABF) tab[idx] = 0.0f;
    }

    const int4 lab = *reinterpret_cast<const int4*>(labels + (size_t)n * HWPX + p);
    const int  lab0 = __shfl(lab.x, 0, 16);
    const bool uni  = (lab.x == lab.y) && (lab.x == lab.z) &&
                      (lab.x == lab.w) && (lab.x == lab0);
    const unsigned long long b = __ballot((int)uni);
    const unsigned long long m = 0xFFFFull << (wgrp * 16);
    if (l16 == 0)
        spanlab[n * SPANS + span] = ((b & m) == m) ? lab0 : -1;
}

__global__ __launch_bounds__(256) void accum_kernel(
    const float* __restrict__ color,
    const int*   __restrict__ labels,
    const int*   __restrict__ spanlab,
    float* __restrict__ tab)
{
    __shared__ float ltab[KSEG * NF];
    const int tid = threadIdx.x;
    for (int i = tid; i < KSEG * NF; i += 256) ltab[i] = 0.0f;
    __syncthreads();

    const int n = blockIdx.y;
    const float* colN = color  + (size_t)n * NCH * HWPX;
    const int*   labN = labels + (size_t)n * HWPX;
    const int*   slN  = spanlab + n * SPANS;

    const int grp = tid >> 4;            // 16 groups
    const int l16 = tid & 15;
    const int h   = grp & 1;             // channel half (0: ch0-7, 1: ch8-15)
    const int cb  = h * 8;               // channel base for this group

    // block covers 8 spans per iteration (2 groups per span)
    for (int sbase = blockIdx.x * 8; sbase < SPANS; sbase += gridDim.x * 8) {
        const int span = sbase + (grp >> 1);
        const int p    = span * 64 + l16 * 4;
        const int slab = slN[span];

        if (slab >= 0) {
            // fast path: 8 independent float4 loads (one per owned channel)
            float fs[8];
            float sq = 0.0f;
            #pragma unroll
            for (int c = 0; c < 8; ++c) {
                const float4 v = *reinterpret_cast<const float4*>(
                    colN + (size_t)(cb + c) * HWPX + p);
                fs[c] = (v.x + v.y) + (v.z + v.w);
                sq += v.x * v.x + v.y * v.y + v.z * v.z + v.w * v.w;
            }
            // reduce-scatter 8 values over 16 lanes; lanes l and l^1 end as
            // a pair owning channel (l16>>1)&7 (both hold the full sum).
            #pragma unroll
            for (int c = 0; c < 4; ++c) {
                const float kp  = (l16 & 8) ? fs[c + 4] : fs[c];
                const float snd = (l16 & 8) ? fs[c] : fs[c + 4];
                fs[c] = kp + __shfl_xor(snd, 8, 16);
            }
            #pragma unroll
            for (int c = 0; c < 2; ++c) {
                const float kp  = (l16 & 4) ? fs[c + 2] : fs[c];
                const float snd = (l16 & 4) ? fs[c] : fs[c + 2];
                fs[c] = kp + __shfl_xor(snd, 4, 16);
            }
            {
                const float kp  = (l16 & 2) ? fs[1] : fs[0];
                const float snd = (l16 & 2) ? fs[0] : fs[1];
                fs[0] = kp + __shfl_xor(snd, 2, 16);
            }
            fs[0] += __shfl_xor(fs[0], 1, 16);
            // sq: full 16-lane sum of this group's half-channels
            sq += __shfl_xor(sq, 8, 16);
            sq += __shfl_xor(sq, 4, 16);
            sq += __shfl_xor(sq, 2, 16);
            sq += __shfl_xor(sq, 1, 16);

            float* seg = ltab + slab * NF;
            if ((l16 & 1) == 0)
                atomicAdd(seg + 2 + cb + ((l16 >> 1) & 7), fs[0]);
            if (l16 == 0) {
                atomicAdd(seg + 1, sq);          // two half-contributions
                if (h == 0) atomicAdd(seg + 0, 64.0f);
            }
        } else {
            // correctness fallback: per-pixel LDS atomics over owned channels
            const int4 lb = *reinterpret_cast<const int4*>(labN + p);
            const int labv[4] = {lb.x, lb.y, lb.z, lb.w};
            for (int i = 0; i < 4; ++i) {
                float sqp = 0.0f;
                float* seg = ltab + labv[i] * NF;
                for (int c = 0; c < 8; ++c) {
                    const float x = colN[(size_t)(cb + c) * HWPX + p + i];
                    sqp += x * x;
                    atomicAdd(seg + 2 + cb + c, x);
                }
                atomicAdd(seg + 1, sqp);
                if (h == 0) atomicAdd(seg + 0, 1.0f);
            }
        }
    }

    __syncthreads();
    // flush (typically 1-2 nonzero segments per block)
    float* tabN = tab + (size_t)n * KSEG * NF;
    for (int i = tid; i < KSEG * NF; i += 256) {
        const float x = ltab[i];
        if (x != 0.0f) atomicAdd(tabN + i, x);
    }
}

__global__ __launch_bounds__(256) void finalize_kernel(
    const float* __restrict__ tab, float* __restrict__ out)
{
    __shared__ float mbg[NIMG][NCH];
    __shared__ float bgcnt[NIMG];
    __shared__ float r0[256], r1[256], r2[256];
    const int tid = threadIdx.x;
    if (tid < NIMG * NCH) {
        const int n = tid / NCH, c = tid % NCH;
        const float* b = tab + (size_t)n * KSEG * NF;   // slot 0 = background
        const float cnt = b[0];
        mbg[n][c] = b[2 + c] / (cnt + EPSV);
        if (c == 0) bgcnt[n] = cnt;
    }
    __syncthreads();

    float vsum = 0.0f, intraS = 0.0f, interS = 0.0f;
    for (int idx = tid; idx < NIMG * KSEG; idx += 256) {
        const int n = idx / KSEG, k = idx % KSEG;
        if (k == 0) continue;
        const float* s = tab + ((size_t)n * KSEG + k) * NF;
        const float cnt = s[0], sq = s[1];
        const float denom = cnt + EPSV;
        float d2 = 0.0f, msf = 0.0f, msm = 0.0f;
        #pragma unroll
        for (int c = 0; c < NCH; ++c) {
            const float f  = s[2 + c];
            const float mu = f / denom;
            msf += mu * f;
            msm += mu * mu;
            const float dd = mu - mbg[n][c];
            d2 += dd * dd;
        }
        const float intra = (sq - 2.0f * msf + cnt * msm) / denom;
        const float dist  = sqrtf(d2 + 1e-12f);
        const float t     = fmaxf(MARGIN - dist, 0.0f);
        const float inter = t * t;
        if ((cnt >= MINPIX) && (bgcnt[n] >= MINPIX)) {
            vsum += 1.0f; intraS += intra; interS += inter;
        }
    }
    r0[tid] = vsum; r1[tid] = intraS; r2[tid] = interS;
    __syncthreads();
    for (int sft = 128; sft; sft >>= 1) {
        if (tid < sft) {
            r0[tid] += r0[tid + sft];
            r1[tid] += r1[tid + sft];
            r2[tid] += r2[tid + sft];
        }
        __syncthreads();
    }
    if (tid == 0) {
        const float total = r0[0];
        const float safe  = fmaxf(total, 1.0f);
        out[0] = (total > 0.0f) ? (r1[0] + LAMBDA * r2[0]) / safe : 0.0f;
    }
}

extern "C" void kernel_launch(void* const* d_in, const int* in_sizes, int n_in,
                              void* d_out, int out_size, void* d_ws, size_t ws_size,
                              hipStream_t stream) {
    const float* color  = (const float*)d_in[0];
    const int*   labels = (const int*)d_in[2];
    float* ws  = (float*)d_ws;
    float* out = (float*)d_out;

    int*   spanlab = (int*)ws;
    float* tab     = ws + WS_TAB;

    dim3 gridA(SPANS / 16, NIMG);    // 256 x 8 blocks; also zeroes tab
    spanlab_kernel<<<gridA, 256, 0, stream>>>(labels, spanlab, tab);

    dim3 gridB(256, NIMG);           // 2048 blocks, 8 spans each, 2 iters
    accum_kernel<<<gridB, 256, 0, stream>>>(color, labels, spanlab, tab);

    finalize_kernel<<<1, 256, 0, stream>>>(tab, out);
}